// Round 14
// baseline (877.130 us; speedup 1.0000x reference)
//
#include <hip/hip_runtime.h>
#include <math.h>

// GRU-RCN bf16 MFMA, round-14: NF=2 (32 out-ch/wave, halves LDS reads/output)
// applied at r11's healthy grid sizes; convC kept at r11's proven NF=1 form.
// B=8,T=16,C=Oh=64,HxW=56x56, 3x3 SAME.
// Per step t:
//   convUW: bid<448 convU(t) [NF=2, full-width, 2 units] -> z, r*h
//           bid>=448: 336 convW(t+1) riders [NF=2, full-width, 4 units]
//   convCX: bid<448 convC(t) [NF=1, r11] -> h', out ; bid>=448 xprep(t+2)
// Layouts:
//   padded imgs (xpad[2]/hpad/rhpad): bf16 [b][58][66][64ci], 16B ci-slices
//     XOR-swizzled by (col&7) -> conflict-free ds_read_b128.
//   wcat: bf16 [plane(ky*3+kx)][o][ci] (W:192, U:128, C:64)
//   wx[2]: bf16 [b][y56][px64][192]; zbuf/hstate: fp16 [b][y][px64][64]

#define PIX 4224                   // 66*64 u16 per padded row
#define PIMG 244992                // 58*PIX u16 per padded image
#define BIMG ((size_t)8 * PIMG)    // u16 per image set (8 batches)
#define WXS ((size_t)5505024)      // u16 per wx slot: 8*56*64*192
#define HL_OFF ((size_t)25690112)  // 8*16*64*3136 floats
#define SLOT 2176                  // u16 per half-width slot (34px x 64ci)
#define SLOTW 4224                 // u16 per full-width slot (66px x 64ci)

typedef unsigned short u16;
typedef __attribute__((ext_vector_type(8))) __bf16 bf16x8;
typedef __attribute__((ext_vector_type(4))) float f32x4;
typedef __attribute__((ext_vector_type(4))) unsigned int u32x4;

__device__ __forceinline__ float bf2f(u16 u) {
  unsigned v = ((unsigned)u) << 16;
  float f;
  __builtin_memcpy(&f, &v, 4);
  return f;
}
__device__ __forceinline__ u16 f2bf(float f) {
  unsigned u;
  __builtin_memcpy(&u, &f, 4);
  u = (u + 0x7FFFu + ((u >> 16) & 1u)) >> 16;  // RNE
  return (u16)u;
}
__device__ __forceinline__ u16 f2h(float f) {
  _Float16 h = (_Float16)f;
  u16 u;
  __builtin_memcpy(&u, &h, 2);
  return u;
}
__device__ __forceinline__ void gll16(const u16* g, u16* l) {
  __builtin_amdgcn_global_load_lds(
      (const __attribute__((address_space(1))) void*)g,
      (__attribute__((address_space(3))) void*)l, 16, 0, 0);
}

#define UNIT_SYNC() \
  asm volatile("s_waitcnt vmcnt(0)" ::: "memory"); \
  __syncthreads();

// ---- staging ---------------------------------------------------------------
__device__ __forceinline__ void stage_row(const u16* img, int prow, int x0,
                                          u16* ring, int slot, int lane,
                                          int wv) {
  const u16* g = img + (size_t)prow * PIX + x0 * 64;
  u16* l = ring + slot * SLOT;
  gll16(g + wv * 512 + lane * 8, l + wv * 512);
  if (wv == 0 && lane < 16) gll16(g + 2048 + lane * 8, l + 2048);
}
__device__ __forceinline__ void stage_rowf(const u16* img, int prow, u16* ring,
                                           int slot, int lane, int wv) {
  const u16* g = img + (size_t)prow * PIX;
  u16* l = ring + slot * SLOTW;
#pragma unroll
  for (int c = wv; c < 8; c += 4) gll16(g + c * 512 + lane * 8, l + c * 512);
  if (wv == 3 && lane < 16) gll16(g + 4096 + lane * 8, l + 4096);
}

// ---- weight fragments -------------------------------------------------------
__device__ __forceinline__ void loadB18(const u16* wr, int NCH,
                                        bf16x8 (&B)[6][3]) {
#pragma unroll
  for (int p = 0; p < 6; ++p) {
    const int ky = p >> 1, kc = p & 1;
#pragma unroll
    for (int kx = 0; kx < 3; ++kx)
      B[p][kx] = *(const bf16x8*)(wr + (size_t)((ky * 3 + kx) * NCH) * 64 +
                                  kc * 32);
  }
}
__device__ __forceinline__ void loadB36(const u16* wr, int NCH,
                                        bf16x8 (&B)[6][3][2]) {
#pragma unroll
  for (int p = 0; p < 6; ++p) {
    const int ky = p >> 1, kc = p & 1;
#pragma unroll
    for (int kx = 0; kx < 3; ++kx)
#pragma unroll
      for (int nf = 0; nf < 2; ++nf)
        B[p][kx][nf] = *(const bf16x8*)(wr + (size_t)((ky * 3 + kx) * NCH) * 64 +
                                        nf * 1024 + kc * 32);
  }
}

// ---- conv units -------------------------------------------------------------
// NF=1, half-width 8-slot ring (convC)
__device__ __forceinline__ void conv_unit(const u16* ring, int rcb,
                                          const bf16x8 (&B)[6][3],
                                          f32x4 (&acc)[2], int lane) {
#pragma unroll
  for (int p = 0; p < 6; ++p) {
    const int ky = p >> 1, kc = p & 1;
    const int slot = (rcb + ky) & 7;
    bf16x8 af[2][3];
#pragma unroll
    for (int mf = 0; mf < 2; ++mf)
#pragma unroll
      for (int kx = 0; kx < 3; ++kx) {
        const int pp = mf * 16 + (lane & 15) + kx;
        const int sl = (kc * 4 + (lane >> 4)) ^ (pp & 7);
        af[mf][kx] = *(const bf16x8*)(ring + slot * SLOT + pp * 64 + sl * 8);
      }
#pragma unroll
    for (int kx = 0; kx < 3; ++kx)
#pragma unroll
      for (int mf = 0; mf < 2; ++mf)
        acc[mf] = __builtin_amdgcn_mfma_f32_16x16x32_bf16(af[mf][kx], B[p][kx],
                                                          acc[mf], 0, 0, 0);
  }
}
// NF=2, full-width 4-slot ring (convU / convW)
__device__ __forceinline__ void conv_unit2(const u16* ring, int rcb,
                                           const bf16x8 (&B)[6][3][2],
                                           f32x4 (&acc)[2][2], int lane,
                                           int x0w) {
#pragma unroll
  for (int p = 0; p < 6; ++p) {
    const int ky = p >> 1, kc = p & 1;
    const int slot = (rcb + ky) & 3;
    bf16x8 af[2][3];
#pragma unroll
    for (int mf = 0; mf < 2; ++mf)
#pragma unroll
      for (int kx = 0; kx < 3; ++kx) {
        const int pp = x0w + mf * 16 + (lane & 15) + kx;
        const int sl = (kc * 4 + (lane >> 4)) ^ (pp & 7);
        af[mf][kx] = *(const bf16x8*)(ring + slot * SLOTW + pp * 64 + sl * 8);
      }
#pragma unroll
    for (int kx = 0; kx < 3; ++kx)
#pragma unroll
      for (int mf = 0; mf < 2; ++mf)
#pragma unroll
        for (int nf = 0; nf < 2; ++nf)
          acc[mf][nf] = __builtin_amdgcn_mfma_f32_16x16x32_bf16(
              af[mf][kx], B[p][kx][nf], acc[mf][nf], 0, 0, 0);
  }
}

// ---- convW role (NF=2): id in [0,336) = ns(3) x b(8) x yq(14); 4 y-units ---
__device__ __forceinline__ void do_convW(const u16* __restrict__ xslot,
                                         const u16* __restrict__ wcat,
                                         u16* __restrict__ wx, int id,
                                         u16* ring, u16* tile) {
  const int ns = id / 112;
  const int rem = id % 112;
  const int b = rem & 7;
  const int y0 = (rem >> 3) * 4;  // 0..52
  const int lane = threadIdx.x & 63, wv = threadIdx.x >> 6;
  const int chs = wv & 1, x0w = (wv >> 1) * 32;
  const int nb = ns * 64 + chs * 32;

  const u16* wr = wcat + (size_t)(nb + (lane & 15)) * 64 + (lane >> 4) * 8;
  bf16x8 B[6][3][2];
  loadB36(wr, 192, B);

  const u16* img = xslot + (size_t)b * PIMG;
#pragma unroll
  for (int k = 0; k < 3; ++k) stage_rowf(img, y0 + k, ring, k, lane, wv);

#pragma unroll
  for (int u = 0; u < 4; ++u) {
    UNIT_SYNC();
    if (u < 3) stage_rowf(img, y0 + u + 3, ring, (u + 3) & 3, lane, wv);

    f32x4 acc[2][2];
#pragma unroll
    for (int mf = 0; mf < 2; ++mf)
#pragma unroll
      for (int nf = 0; nf < 2; ++nf) acc[mf][nf] = (f32x4){0.f, 0.f, 0.f, 0.f};
    conv_unit2(ring, u, B, acc, lane, x0w);

    const int y = y0 + u;
    const size_t rowb = ((size_t)(b * 56) + y) * 64;
#pragma unroll
    for (int mf = 0; mf < 2; ++mf)
#pragma unroll
      for (int nf = 0; nf < 2; ++nf) {
        const int cl = chs * 32 + nf * 16 + (lane & 15);
#pragma unroll
        for (int r = 0; r < 4; ++r) {
          const int pl = x0w + mf * 16 + 4 * (lane >> 4) + r;
          tile[pl * 64 + cl] = f2bf(acc[mf][nf][r]);
        }
      }
    __syncthreads();
#pragma unroll
    for (int j = 0; j < 2; ++j) {
      const int idx = j * 256 + threadIdx.x;
      const int pl = idx >> 3, off = idx & 7;
      *(u32x4*)(wx + (rowb + pl) * 192 + ns * 64 + off * 8) =
          *(const u32x4*)(tile + pl * 64 + off * 8);
    }
  }
}

// ---- xprep row (2-pass, 29KB scratch: fits in ring) -------------------------
__device__ __forceinline__ void xprep_row(const float* __restrict__ x,
                                          u16* __restrict__ dst, int t, int b,
                                          int y, float (*tx)[57]) {
  const int tid = threadIdx.x;
  const size_t pb = (size_t)b * PIMG + (size_t)(y + 1) * PIX;
#pragma unroll
  for (int half = 0; half < 2; ++half) {
    __syncthreads();
    for (int i = tid; i < 32 * 56; i += 256) {
      int cl = i / 56, px = i % 56;
      tx[cl][px] =
          x[((size_t)(b * 16 + t) * 64 + half * 32 + cl) * 3136 + y * 56 + px];
    }
    __syncthreads();
    for (int i = tid; i < 56 * 32; i += 256) {
      int px = i / 32, cl = i % 32;
      int ci = half * 32 + cl;
      int gx = px + 1;
      dst[pb + gx * 64 + (((ci >> 3) ^ (gx & 7)) << 3) + (ci & 7)] =
          f2bf(tx[cl][px]);
    }
  }
}

// ---- prep kernels -----------------------------------------------------------
__global__ __launch_bounds__(256) void wprep_k(const float* __restrict__ W,
                                               const float* __restrict__ U,
                                               const float* __restrict__ C,
                                               u16* __restrict__ wcat) {
  int i = blockIdx.x * 256 + threadIdx.x;
  if (i >= 221184) return;
  float v;
  if (i < 110592) {  // W: [9][192][64]
    int plane = i / 12288, rem = i % 12288, o = rem / 64, ci = rem % 64;
    v = W[(size_t)(o * 64 + ci) * 9 + plane];
  } else if (i < 184320) {  // U: [9][128][64]
    int j = i - 110592;
    int plane = j / 8192, rem = j % 8192, o = rem / 64, ci = rem % 64;
    v = U[(size_t)(o * 64 + ci) * 9 + plane];
  } else {  // C: [9][64][64]
    int j = i - 184320;
    int plane = j / 4096, rem = j % 4096, o = rem / 64, ci = rem % 64;
    v = C[(size_t)(o * 64 + ci) * 9 + plane];
  }
  wcat[i] = f2bf(v);
}

__global__ __launch_bounds__(256) void hinit_k(const float* __restrict__ h,
                                               u16* __restrict__ hpad,
                                               _Float16* __restrict__ hstate) {
  __shared__ float t[64][57];
  const int y = blockIdx.x, b = blockIdx.y;
  const int tid = threadIdx.x;
  for (int i = tid; i < 64 * 56; i += 256) {
    int ci = i / 56, xx = i % 56;
    t[ci][xx] = h[((size_t)(b * 64) + ci) * 3136 + y * 56 + xx];
  }
  __syncthreads();
  const size_t pb = (size_t)b * PIMG + (size_t)(y + 1) * PIX;
  const size_t sb = ((size_t)(b * 56) + y) * 64;
  for (int i = tid; i < 56 * 64; i += 256) {
    int px = i / 64, ci = i % 64;
    float v = t[ci][px];
    int gx = px + 1;
    hpad[pb + gx * 64 + (((ci >> 3) ^ (gx & 7)) << 3) + (ci & 7)] = f2bf(v);
    hstate[(sb + px) * 64 + ci] = (_Float16)v;
  }
}

__global__ __launch_bounds__(256) void xprep01_k(const float* __restrict__ x,
                                                 u16* __restrict__ x0,
                                                 u16* __restrict__ x1) {
  __shared__ float tt[32][57];
  const int t = blockIdx.y;
  xprep_row(x, t ? x1 : x0, t, blockIdx.x & 7, blockIdx.x >> 3, tt);
}

__global__ __launch_bounds__(256, 2) void convW0_k(const u16* __restrict__ xs,
                                                   const u16* __restrict__ wcat,
                                                   u16* __restrict__ wx) {
  __shared__ __align__(16) u16 ring[4 * SLOTW];
  __shared__ __align__(16) u16 tile[64 * 64];
  do_convW(xs, wcat, wx, blockIdx.x, ring, tile);
}

// ---- convUW: convU(t) [bid<448, NF=2] || convW(t+1) riders [336] -----------
__global__ __launch_bounds__(256, 2) void convUW_k(
    const u16* __restrict__ hpad, const u16* __restrict__ xpad_n,
    const u16* __restrict__ wcat, const u16* __restrict__ wx_c,
    u16* __restrict__ wx_n, _Float16* __restrict__ zbuf,
    u16* __restrict__ rhpad) {
  __shared__ __align__(16) u16 ring[4 * SLOTW];
  __shared__ __align__(16) u16 tile[64 * 64];
  const int bid = blockIdx.x;
  if (bid >= 448) {
    do_convW(xpad_n, wcat, wx_n, bid - 448, ring, tile);
    return;
  }
  const int ns = bid / 224;  // 0: z-gate, 1: r-gate
  const int rem = bid % 224;
  const int b = rem & 7;
  const int y0 = (rem >> 3) * 2;  // 0..54
  const int lane = threadIdx.x & 63, wv = threadIdx.x >> 6;
  const int chs = wv & 1, x0w = (wv >> 1) * 32;
  const int nb = ns * 64 + chs * 32;  // U-channel base

  const u16* wr =
      wcat + 110592 + (size_t)(nb + (lane & 15)) * 64 + (lane >> 4) * 8;
  bf16x8 B[6][3][2];
  loadB36(wr, 128, B);

  const u16* img = hpad + (size_t)b * PIMG;
#pragma unroll
  for (int k = 0; k < 3; ++k) stage_rowf(img, y0 + k, ring, k, lane, wv);

#pragma unroll
  for (int u = 0; u < 2; ++u) {
    UNIT_SYNC();
    if (u == 0) stage_rowf(img, y0 + 3, ring, 3, lane, wv);

    const int y = y0 + u;
    const size_t rowb = ((size_t)(b * 56) + y) * 64;

    // prefetch wx for this unit (latency hides under the 72 MFMAs)
    u16 wxv[2][2][4];
#pragma unroll
    for (int nf = 0; nf < 2; ++nf)
#pragma unroll
      for (int mf = 0; mf < 2; ++mf)
#pragma unroll
        for (int r = 0; r < 4; ++r) {
          const int pg = x0w + mf * 16 + 4 * (lane >> 4) + r;
          wxv[nf][mf][r] =
              wx_c[(rowb + pg) * 192 + nb + nf * 16 + (lane & 15)];
        }

    f32x4 acc[2][2];
#pragma unroll
    for (int mf = 0; mf < 2; ++mf)
#pragma unroll
      for (int nf = 0; nf < 2; ++nf) acc[mf][nf] = (f32x4){0.f, 0.f, 0.f, 0.f};
    conv_unit2(ring, u, B, acc, lane, x0w);

#pragma unroll
    for (int mf = 0; mf < 2; ++mf)
#pragma unroll
      for (int nf = 0; nf < 2; ++nf) {
        const int cl = chs * 32 + nf * 16 + (lane & 15);
#pragma unroll
        for (int r = 0; r < 4; ++r) {
          const int pl = x0w + mf * 16 + 4 * (lane >> 4) + r;
          const float a = bf2f(wxv[nf][mf][r]) + acc[mf][nf][r];
          const float s = 1.f / (1.f + __expf(-a));
          if (ns == 0) {
            tile[pl * 64 + cl] = f2h(s);
          } else {
            const int gx = pl + 1;
            const int sw = (((cl >> 3) ^ (gx & 7)) << 3) | (cl & 7);
            const float hv = bf2f(ring[((u + 1) & 3) * SLOTW + gx * 64 + sw]);
            tile[pl * 64 + sw] = f2bf(s * hv);
          }
        }
      }
    __syncthreads();
#pragma unroll
    for (int j = 0; j < 2; ++j) {
      const int idx = j * 256 + threadIdx.x;
      const int pl = idx >> 3, off = idx & 7;
      const u32x4 vv = *(const u32x4*)(tile + pl * 64 + off * 8);
      if (ns == 0) {
        *(u32x4*)((u16*)zbuf + (rowb + pl) * 64 + off * 8) = vv;
      } else if (pl < 56) {
        *(u32x4*)(rhpad + (size_t)b * PIMG + (size_t)(y + 1) * PIX +
                  (pl + 1) * 64 + off * 8) = vv;
      }
    }
  }
}

// ---- convCX: convC(t) [bid<448, r11 NF=1] || xprep(t+2) [448 riders] --------
__global__ __launch_bounds__(256, 3) void convCX_k(
    const float* __restrict__ x, u16* __restrict__ xpad_w,
    const u16* __restrict__ rhpad, const u16* __restrict__ wcat,
    const u16* __restrict__ wx_c, const _Float16* __restrict__ zbuf,
    _Float16* __restrict__ hstate, u16* __restrict__ hpad,
    float* __restrict__ out, int t) {
  __shared__ __align__(16) u16 ring[8 * SLOT];
  __shared__ float ldt[4][16][33];
  const int bid = blockIdx.x;
  if (bid >= 448) {
    const int id = bid - 448;
    xprep_row(x, xpad_w, t + 2, id & 7, id >> 3, (float(*)[57])ring);
    return;
  }
  const int b = bid & 7;
  const int r2 = bid >> 3;       // 0..55
  const int x0 = (r2 & 1) * 32;
  const int y0 = (r2 >> 1) * 2;  // 0..54
  const int lane = threadIdx.x & 63, wv = threadIdx.x >> 6;
  const int nl = wv * 16 + (lane & 15);  // 0..63

  const u16* wr = wcat + 184320 + (size_t)nl * 64 + (lane >> 4) * 8;
  bf16x8 B[6][3];
  loadB18(wr, 64, B);

  const u16* img = rhpad + (size_t)b * PIMG;
#pragma unroll
  for (int k = 0; k < 3; ++k) stage_row(img, y0 + k, x0, ring, k, lane, wv);

#pragma unroll
  for (int u = 0; u < 2; ++u) {
    UNIT_SYNC();
    if (u == 0) stage_row(img, y0 + 3, x0, ring, 3, lane, wv);

    const int y = y0 + u;
    const size_t rowb = ((size_t)(b * 56) + y) * 64;

    // prefetch epilogue operands (wx, z, h) — hides scattered 2B loads
    u16 wxv[2][4];
    _Float16 zv[2][4], hv[2][4];
#pragma unroll
    for (int mf = 0; mf < 2; ++mf)
#pragma unroll
      for (int r = 0; r < 4; ++r) {
        const int pg = x0 + mf * 16 + 4 * (lane >> 4) + r;
        wxv[mf][r] = wx_c[(rowb + pg) * 192 + 128 + nl];
        zv[mf][r] = zbuf[(rowb + pg) * 64 + nl];
        hv[mf][r] = hstate[(rowb + pg) * 64 + nl];
      }

    f32x4 acc[2] = {{0.f, 0.f, 0.f, 0.f}, {0.f, 0.f, 0.f, 0.f}};
    conv_unit(ring, u, B, acc, lane);

#pragma unroll
    for (int mf = 0; mf < 2; ++mf)
#pragma unroll
      for (int r = 0; r < 4; ++r) {
        const int px = x0 + mf * 16 + 4 * (lane >> 4) + r;
        float hn = 0.f;
        if (px < 56) {
          const float a = bf2f(wxv[mf][r]) + acc[mf][r];
          const float htil = tanhf(a);
          const float z = (float)zv[mf][r];
          const float ho = (float)hv[mf][r];
          hn = fmaf(z, htil - ho, ho);
          hstate[(rowb + px) * 64 + nl] = (_Float16)hn;
          const int gx = px + 1;
          hpad[(size_t)b * PIMG + (size_t)(y + 1) * PIX + gx * 64 +
               (((nl >> 3) ^ (gx & 7)) << 3) + (nl & 7)] = f2bf(hn);
        }
        ldt[wv][lane & 15][mf * 16 + 4 * (lane >> 4) + r] = hn;
      }
    __syncthreads();
    const int xl = lane & 31;
    const int px = x0 + xl;
    if (px < 56) {
#pragma unroll
      for (int cc = 0; cc < 8; ++cc) {
        const int ch = (lane >> 5) * 8 + cc;
        const float v = ldt[wv][ch][xl];
        const int oc = wv * 16 + ch;
        out[(((size_t)(b * 16 + t)) * 64 + oc) * 3136 + y * 56 + px] = v;
        if (t == 15)
          out[HL_OFF + ((size_t)(b * 64) + oc) * 3136 + y * 56 + px] = v;
      }
    }
    __syncthreads();  // ldt reuse guard across units
  }
}

extern "C" void kernel_launch(void* const* d_in, const int* in_sizes, int n_in,
                              void* d_out, int out_size, void* d_ws,
                              size_t ws_size, hipStream_t stream) {
  const float* x = (const float*)d_in[0];
  const float* h = (const float*)d_in[1];
  const float* W = (const float*)d_in[2];
  const float* U = (const float*)d_in[3];
  const float* C = (const float*)d_in[4];
  float* out = (float*)d_out;

  u16* ws_u = (u16*)d_ws;
  u16* xpad = ws_u;                             // 2 slots x BIMG
  u16* hpad = xpad + 2 * BIMG;                  // BIMG
  u16* rhpad = hpad + BIMG;                     // BIMG
  u16* wcat = rhpad + BIMG;                     // 221,184
  u16* wxr = wcat + 221184;                     // 2 slots x WXS
  _Float16* zbuf = (_Float16*)(wxr + 2 * WXS);  // 1,835,008 fp16
  _Float16* hstate = zbuf + 1835008;            // 1,835,008 fp16

  // zero the 4 padded images (borders must stay 0)
  hipMemsetAsync(d_ws, 0, (size_t)4 * BIMG * sizeof(u16), stream);
  wprep_k<<<864, 256, 0, stream>>>(W, U, C, wcat);
  hinit_k<<<dim3(56, 8), 256, 0, stream>>>(h, hpad, hstate);
  xprep01_k<<<dim3(448, 2), 256, 0, stream>>>(x, xpad, xpad + BIMG);
  convW0_k<<<336, 256, 0, stream>>>(xpad, wcat, wxr);  // wx(0) -> slot 0

  for (int t = 0; t < 16; ++t) {
    u16* xn = xpad + (size_t)((t + 1) & 1) * BIMG;  // x(t+1) image
    u16* xw = xpad + (size_t)(t & 1) * BIMG;        // xprep(t+2) target
    const u16* wxc = wxr + (size_t)(t & 1) * WXS;   // wx(t)
    u16* wxn = wxr + (size_t)((t + 1) & 1) * WXS;   // wx(t+1)

    const int nbA = 448 + ((t < 15) ? 336 : 0);
    convUW_k<<<nbA, 256, 0, stream>>>(hpad, xn, wcat, wxc, wxn, zbuf, rhpad);

    const int nbB = 448 + ((t < 14) ? 448 : 0);
    convCX_k<<<nbB, 256, 0, stream>>>(x, xw, rhpad, wcat, wxc, zbuf, hstate,
                                      hpad, out, t);
  }
}